// Round 14
// baseline (668.826 us; speedup 1.0000x reference)
//
#include <hip/hip_runtime.h>
#include <math.h>

// SymmetricKMeans MI355X — R26: 4-wave FPS. R25 split: fps 283us (51%, ONE wave
// per CU; ~700cy/pick = 144cy distance-issue + reduce + ds_read) / kmeans 267us.
// Distance work is data-parallel; only the pick decision is serial. New fps:
// 256 thr (4 waves), 4 pts/lane (2 packed pairs) -> distance-issue 144->36cy
// (4 SIMDs in parallel); per-lane tree 8->3 combines; cross-wave combine via
// R15's PROVEN paired-DPP reduce (6 fused steps, absmax 0 in R15) -> lane63 of
// each wave writes (max,min-idx) to LDS; ONE syncthreads per pick with parity
// double-buffered slots (runahead wave writes par^1 while others read par —
// disjoint, race-free); all threads combine the 4 wave winners in registers
// (total order => any combine order bit-exact = reference first-max), uniform
// 'last', no readlane. kmeans byte-identical to R25 (553us best, absmax 0).

#define NGRP   80
#define NPTS   1024
#define NCTR   512
#define MAXIT  300
#define NTHR   1024
#define NTHRF  256
#define RING   64
#define LEAD   48
#define OUT_CENT  81920
#define OUT_SCORE 204800

typedef float v2f __attribute__((ext_vector_type(2)));
static __device__ __forceinline__ v2f mk2(float a, float b) {
  v2f r; r.x = a; r.y = b; return r;
}

__device__ float4   g_cent[NGRP * NCTR];            // FPS output -> kmeans init
__device__ int      g_rcls[RING][NGRP * NPTS];      // per-iteration cls ring
__device__ float4   g_rcent[RING][NGRP * NCTR];     // per-iteration centroid ring
__device__ unsigned g_conv32[MAXIT][32];            // bytes[0..79]: 0=open/1=nc/2=conv
__device__ unsigned g_T[32];                        // 0 unset, else T (iters run)
__device__ unsigned g_water[32];                    // contiguous closed prefix

// ---------------- threefry2x32, exactly as JAX (partitionable path) ----------------
__device__ __forceinline__ void tf2x32(unsigned k0, unsigned k1,
                                       unsigned x0, unsigned x1,
                                       unsigned &o0, unsigned &o1) {
  unsigned ks2 = k0 ^ k1 ^ 0x1BD11BDAu;
#define RND(r) { x0 += x1; x1 = (x1 << (r)) | (x1 >> (32 - (r))); x1 ^= x0; }
  x0 += k0; x1 += k1;
  RND(13) RND(15) RND(26) RND(6)
  x0 += k1;  x1 += ks2 + 1u;
  RND(17) RND(29) RND(16) RND(24)
  x0 += ks2; x1 += k0 + 2u;
  RND(13) RND(15) RND(26) RND(6)
  x0 += k0;  x1 += k1 + 3u;
  RND(17) RND(29) RND(16) RND(24)
  x0 += k1;  x1 += ks2 + 4u;
  RND(13) RND(15) RND(26) RND(6)
  x0 += ks2; x1 += k0 + 5u;
#undef RND
  o0 = x0; o1 = x1;
}

// (max value, min index) selection — total order, any reduction order is exact.
__device__ __forceinline__ void fps_comb(float &bv, int &bi, float ov, int oi) {
  if (ov > bv || (ov == bv && oi < bi)) { bv = ov; bi = oi; }
}

// Paired DPP combine step (R15-proven): masked-out lanes receive old=0 and may
// self-corrupt — confined to lanes the lane-63 chain never reads.
#define DPP_CMB(CTRL, RM) {                                                 \
    float ov_ = __int_as_float(__builtin_amdgcn_update_dpp(                 \
        0, __float_as_int(bv), (CTRL), (RM), 0xF, true));                   \
    int oi_ = __builtin_amdgcn_update_dpp(0, bi, (CTRL), (RM), 0xF, true);  \
    fps_comb(bv, bi, ov_, oi_); }

// 64-lane inclusive int scan (LLVM AtomicOptimizer sequence; integer => exact)
__device__ __forceinline__ int wave_iscan(int x) {
  x += __builtin_amdgcn_update_dpp(0, x, 0x111, 0xF, 0xF, true); // row_shr:1
  x += __builtin_amdgcn_update_dpp(0, x, 0x112, 0xF, 0xF, true); // row_shr:2
  x += __builtin_amdgcn_update_dpp(0, x, 0x114, 0xF, 0xF, true); // row_shr:4
  x += __builtin_amdgcn_update_dpp(0, x, 0x118, 0xF, 0xF, true); // row_shr:8
  x += __builtin_amdgcn_update_dpp(0, x, 0x142, 0xA, 0xF, true); // row_bcast:15
  x += __builtin_amdgcn_update_dpp(0, x, 0x143, 0xC, 0xF, true); // row_bcast:31
  return x;
}

// sweep helper: closed (all 80 bytes nonzero) / allconv (all == 2); relaxed.
__device__ __forceinline__ void conv_scan(unsigned w, bool &closed, bool &allc) {
  unsigned hz = 0u; bool ac = true;
#pragma unroll
  for (int i = 0; i < 20; ++i) {
    unsigned d = __hip_atomic_load(&g_conv32[w][i], __ATOMIC_RELAXED,
                                   __HIP_MEMORY_SCOPE_AGENT);
    hz |= (d - 0x01010101u) & ~d & 0x80808080u;   // haszero(d)
    ac = ac && (d == 0x02020202u);
  }
  closed = (hz == 0u); allc = ac;
}

// ---------------- FPS: FOUR waves per group, 4 points/lane, packed pairs ----------------
__global__ __launch_bounds__(NTHRF) void fps_kernel(const float *__restrict__ pos) {
  const int g = blockIdx.x, t = threadIdx.x;
  const int e = g & 7;
  const int lane = t & 63, w = t >> 6;
  __shared__ float4 sp4[NPTS];
  __shared__ float  swv[2][4];
  __shared__ int    swi[2][4];
  {  // distributed kmeans-sync-state re-init (graph-safe; kmeans launches after)
    const int gid = g * NTHRF + t, stride = NGRP * NTHRF;
    for (int k = gid; k < MAXIT * 32; k += stride) g_conv32[0][k] = 0u;
    if (gid == 0) { g_T[0] = 0u; g_water[0] = 0u; }
  }
  unsigned s0, s1, o0, o1;            // partitionable split + random_bits
  tf2x32(0u, 1u, 0u, 1u, s0, s1);
  tf2x32(s0, s1, 0u, (unsigned)g, o0, o1);
  int last = (int)((o0 ^ o1) & 1023u);

  const float *p = pos + (size_t)e * NPTS * 3;
  v2f xp[2], yp[2], zp[2], mdp[2];
#pragma unroll
  for (int q = 0; q < 2; ++q) {       // pair q = points (2q)*256+t, (2q+1)*256+t
    int n0 = (2 * q) * NTHRF + t, n1 = (2 * q + 1) * NTHRF + t;
    xp[q] = mk2(p[n0 * 3 + 0], p[n1 * 3 + 0]);
    yp[q] = mk2(p[n0 * 3 + 1], p[n1 * 3 + 1]);
    zp[q] = mk2(p[n0 * 3 + 2], p[n1 * 3 + 2]);
    sp4[n0] = make_float4(xp[q].x, yp[q].x, zp[q].x, 0.f);
    sp4[n1] = make_float4(xp[q].y, yp[q].y, zp[q].y, 0.f);
    mdp[q] = mk2(__int_as_float(0x7f800000), __int_as_float(0x7f800000));
  }
  __syncthreads();                    // sp4 visible to all 4 waves
  for (int j = 0; j < NCTR; ++j) {
    const float4 L = sp4[last];       // uniform b128 broadcast read
    if (t == 0) {   // centroid j = p[last]; c2 plain chain (unchanged)
      float c2 = __fadd_rn(__fadd_rn(__fmul_rn(L.x, L.x), __fmul_rn(L.y, L.y)),
                           __fmul_rn(L.z, L.z));
      g_cent[(size_t)g * NCTR + j] = make_float4(L.x, L.y, L.z, c2);
    }
    {
#pragma clang fp contract(off)
      // packed distances: identical per-element op sequence (sub,mul,add,add,min)
      const v2f lx2 = mk2(L.x, L.x), ly2 = mk2(L.y, L.y), lz2 = mk2(L.z, L.z);
#pragma unroll
      for (int q = 0; q < 2; ++q) {
        v2f dx = xp[q] - lx2, dy = yp[q] - ly2, dz = zp[q] - lz2;
        v2f d = (dx * dx + dy * dy) + dz * dz;
        mdp[q] = __builtin_elementwise_min(mdp[q], d);   // == fminf per elem
      }
    }
    // ---- per-lane paired tree over 4 candidates (exact total order) ----
    float bv = mdp[0].x; int bi = t;
    fps_comb(bv, bi, mdp[0].y, NTHRF + t);
    float bv2 = mdp[1].x; int bi2 = 2 * NTHRF + t;
    fps_comb(bv2, bi2, mdp[1].y, 3 * NTHRF + t);
    fps_comb(bv, bi, bv2, bi2);
    // ---- within-wave paired DPP reduce (R15-proven) -> lane 63 winner ----
    DPP_CMB(0x121, 0xF)   // row_ror:1
    DPP_CMB(0x122, 0xF)   // row_ror:2
    DPP_CMB(0x124, 0xF)   // row_ror:4
    DPP_CMB(0x128, 0xF)   // row_ror:8
    DPP_CMB(0x142, 0xA)   // row_bcast:15 (rows 1,3)
    DPP_CMB(0x143, 0xC)   // row_bcast:31 (rows 2,3) -> lane 63 = wave winner
    const int par = j & 1;            // parity double-buffer (runahead-safe)
    if (lane == 63) { swv[par][w] = bv; swi[par][w] = bi; }
    __syncthreads();                  // one barrier per pick
    float cv = swv[par][0]; int ci = swi[par][0];
    fps_comb(cv, ci, swv[par][1], swi[par][1]);
    fps_comb(cv, ci, swv[par][2], swi[par][2]);
    fps_comb(cv, ci, swv[par][3], swi[par][3]);
    last = ci;                        // uniform across all threads (same LDS)
  }
}

// ---------------- persistent decoupled k-means: 1 block = 1 group ----------------
__global__ __launch_bounds__(NTHR) void kmeans_kernel(
    const float *__restrict__ pos, float *__restrict__ out) {
  const int g = blockIdx.x, t = threadIdx.x;
  const int e = g & 7;
  const int lane = t & 63, wv = t >> 6;

  // centroid LDS in stripe-pair layout (R16): scp[q] = {x_a,x_b,y_a,y_b,z_a,z_b,w_a,w_b}
  __shared__ float  scp[NCTR / 2][8];
  __shared__ float  spx[NPTS], spy[NPTS], spz[NPTS];
  __shared__ int    slab[NPTS];
  __shared__ int    cnt[NCTR], offs[NCTR];
  __shared__ int    idx[NPTS];
  __shared__ float  redf[16];
  __shared__ double redd[4];
  __shared__ int    swtot[8];
  __shared__ unsigned s_ctl;

  const int cc7 = t & 127, cbid = (t >> 7) & 3;
  const int cq = cc7 + (cbid >> 1) * 128, cs = cbid & 1;  // centroid t's LDS slot

  {  // stage points + initial centroids (once)
    const float *gp = pos + (size_t)e * NPTS * 3;
    spx[t] = gp[t * 3 + 0]; spy[t] = gp[t * 3 + 1]; spz[t] = gp[t * 3 + 2];
    if (t < NCTR) {
      float4 cc = g_cent[(size_t)g * NCTR + t];
      scp[cq][0 + cs] = cc.x; scp[cq][2 + cs] = cc.y;
      scp[cq][4 + cs] = cc.z; scp[cq][6 + cs] = cc.w;
    }
    if (t == 0) s_ctl = 0u;
  }
  __syncthreads();

  const float px = spx[t], py = spy[t], pz = spz[t];
  const float p2 = __fadd_rn(__fadd_rn(__fmul_rn(px, px), __fmul_rn(py, py)),
                             __fmul_rn(pz, pz));
  const v2f px2 = mk2(px, px), py2 = mk2(py, py), pz2 = mk2(pz, pz);
  const v2f p22 = mk2(p2, p2), nw2 = mk2(-2.0f, -2.0f);

  int done_sT = -1;
  for (int it = 0; it < MAXIT; ++it) {
    // ---- phase A: stripe-4 argmin, packed pairs. fma(-2,t0,p2) is bit-equal
    // to (p2 - 2*t0): 2*t0 is exact (exponent bump), one rounding either way.
    float best0 = __int_as_float(0x7f800000), best1 = best0,
          best2 = best0, best3 = best0;
    int im0 = 0, im1 = 0, im2 = 0, im3 = 0;
    {
#pragma clang fp contract(off)
#pragma unroll 2
      for (int m = 0; m < NCTR / 4; ++m) {
        const float4 lo0 = *(const float4 *)&scp[m][0];       // x_a x_b y_a y_b
        const float4 hi0 = *(const float4 *)&scp[m][4];       // z_a z_b w_a w_b
        const float4 lo1 = *(const float4 *)&scp[m + 128][0];
        const float4 hi1 = *(const float4 *)&scp[m + 128][4];
        v2f t0 = px2 * mk2(lo0.x, lo0.y);                     // mul
        t0 = __builtin_elementwise_fma(py2, mk2(lo0.z, lo0.w), t0);  // fma
        t0 = __builtin_elementwise_fma(pz2, mk2(hi0.x, hi0.y), t0);  // fma
        v2f dA = __builtin_elementwise_fma(nw2, t0, p22) + mk2(hi0.z, hi0.w);
        v2f t1 = px2 * mk2(lo1.x, lo1.y);
        t1 = __builtin_elementwise_fma(py2, mk2(lo1.z, lo1.w), t1);
        t1 = __builtin_elementwise_fma(pz2, mk2(hi1.x, hi1.y), t1);
        v2f dB = __builtin_elementwise_fma(nw2, t1, p22) + mk2(hi1.z, hi1.w);
        float d0 = dA.x, d1 = dA.y, d2 = dB.x, d3 = dB.y;
        if (d0 < best0) { best0 = d0; im0 = m; }
        if (d1 < best1) { best1 = d1; im1 = m; }
        if (d2 < best2) { best2 = d2; im2 = m; }
        if (d3 < best3) { best3 = d3; im3 = m; }
      }
    }
    float best = best0; int bm = im0;                 // stripe priority = m order
    if (best1 < best) { best = best1; bm = 128 + im1; }
    if (best2 < best) { best = best2; bm = 256 + im2; }
    if (best3 < best) { best = best3; bm = 384 + im3; }
    const int slot = it & (RING - 1);
    g_rcls[slot][(size_t)g * NPTS + t] = bm;          // self-read ring (no fence)
    slab[t] = bm;
    if (t < NCTR) cnt[t] = 0;                         // merged into B1 region
    if (t == 0)                                       // fresh T read (R23)
      s_ctl = __hip_atomic_load(&g_T[0], __ATOMIC_RELAXED,
                                __HIP_MEMORY_SCOPE_AGENT);
    __syncthreads();                                  // B1 (publishes s_ctl)

    // ---- exit check: s_ctl = freshest known T ----
    {
      const unsigned tv = s_ctl;
      if (it > 0 && tv != 0u && (int)tv <= it) {      // ring slot T-1 complete
        done_sT = (int)tv - 1;
        break;
      }
    }

    // ---- phase B (single block; same f32 op order as R16-R25) ----
    atomicAdd(&cnt[slab[t]], 1);                      // 1024 integer adds
    __syncthreads();
    int sc = 0;
    if (t < NCTR) {                                   // DPP scan (waves 0..7)
      sc = wave_iscan(cnt[t]);
      if (lane == 63) swtot[wv] = sc;
    }
    __syncthreads();
    if (t < NCTR) {
      int pre = 0;
#pragma unroll
      for (int w = 0; w < 8; ++w) pre += (w < wv) ? swtot[w] : 0;
      offs[t] = sc + pre;                             // incl[t]
      cnt[t] = 0;                                     // reuse as wctr
    }
    __syncthreads();
    {
      int c0 = slab[t]; int sl0 = atomicAdd(&cnt[c0], 1);
      idx[(c0 ? offs[c0 - 1] : 0) + sl0] = t;         // scatter (sorted below)
    }
    __syncthreads();
    float mx = 0.0f;
    if (t < NCTR) {
      const int c = t;                                // one centroid per thread
      const int base = c ? offs[c - 1] : 0;
      const int kk = offs[c] - base;
      for (int i = base + 1; i < base + kk; ++i) {    // ascending point order
        int v = idx[i], j = i - 1;
        while (j >= base && idx[j] > v) { idx[j + 1] = idx[j]; --j; }
        idx[j + 1] = v;
      }
      float4 oldc;                                    // gather from pair layout
      oldc.x = scp[cq][0 + cs]; oldc.y = scp[cq][2 + cs];
      oldc.z = scp[cq][4 + cs]; oldc.w = scp[cq][6 + cs];
      float nx, ny, nz;
      if (kk > 0) {
        float sxx = 0.f, syy = 0.f, szz = 0.f;
        for (int i = 0; i < kk; ++i) {                // same adds, same order
          int n2 = idx[base + i];
          sxx = __fadd_rn(sxx, spx[n2]);
          syy = __fadd_rn(syy, spy[n2]);
          szz = __fadd_rn(szz, spz[n2]);
        }
        float fc = (float)kk;
        nx = __fdiv_rn(sxx, fc); ny = __fdiv_rn(syy, fc); nz = __fdiv_rn(szz, fc);
      } else { nx = oldc.x; ny = oldc.y; nz = oldc.z; }
      float dx = __fsub_rn(oldc.x, nx), dy = __fsub_rn(oldc.y, ny),
            dz = __fsub_rn(oldc.z, nz);
      float nr = __fsqrt_rn(__fadd_rn(__fadd_rn(__fmul_rn(dx, dx), __fmul_rn(dy, dy)),
                                      __fmul_rn(dz, dz)));
      mx = nr;
      float c2v2 = __fadd_rn(__fadd_rn(__fmul_rn(nx, nx), __fmul_rn(ny, ny)),
                             __fmul_rn(nz, nz));
      scp[cq][0 + cs] = nx; scp[cq][2 + cs] = ny;     // LDS-persistent update
      scp[cq][4 + cs] = nz; scp[cq][6 + cs] = c2v2;
      g_rcent[slot][(size_t)g * NCTR + t] =           // self-read ring snapshot
          make_float4(nx, ny, nz, c2v2);
    }
    for (int off = 32; off; off >>= 1) {              // wave max (waves 8-15: 0)
      float o = __shfl_down(mx, off, 64);
      if (o > mx) mx = o;
    }
    if (lane == 0) redf[wv] = mx;
    __syncthreads();                                  // E1: redf + scp complete

    // ---- control (t0 only, ALL RELAXED — no cache-maintenance ops) ----
    if (t == 0) {
      unsigned Tl = __hip_atomic_load(&g_T[0], __ATOMIC_RELAXED, __HIP_MEMORY_SCOPE_AGENT);
      if (Tl == 0u) {
        float bmx = fmaxf(fmaxf(fmaxf(redf[0], redf[1]), fmaxf(redf[2], redf[3])),
                          fmaxf(fmaxf(redf[4], redf[5]), fmaxf(redf[6], redf[7])));
        unsigned char cv = (bmx < 1e-3f) ? (unsigned char)2 : (unsigned char)1;
        __hip_atomic_store((unsigned char *)&g_conv32[it][0] + g, cv,
                           __ATOMIC_RELAXED, __HIP_MEMORY_SCOPE_AGENT);
        if (g == 0) {                                 // sweeper
          unsigned w = __hip_atomic_load(&g_water[0], __ATOMIC_RELAXED,
                                         __HIP_MEMORY_SCOPE_AGENT);
          const unsigned w0 = w;
          while (w <= (unsigned)it) {
            bool closed, allc; conv_scan(w, closed, allc);
            if (!closed) break;
            if (allc) {                               // first all-conv t => T
              Tl = w + 1u;
              __hip_atomic_store(&g_T[0], Tl, __ATOMIC_RELAXED, __HIP_MEMORY_SCOPE_AGENT);
              ++w; break;
            }
            ++w;
          }
          if (w != w0)
            __hip_atomic_store(&g_water[0], w, __ATOMIC_RELAXED, __HIP_MEMORY_SCOPE_AGENT);
        }
        if (Tl == 0u)
          Tl = __hip_atomic_load(&g_T[0], __ATOMIC_RELAXED, __HIP_MEMORY_SCOPE_AGENT);
      }
      if (Tl == 0u && it + 1 >= LEAD) {               // ring overwrite guard
        long long guard = 0;
        for (;;) {
          unsigned wv2 = __hip_atomic_load(&g_water[0], __ATOMIC_RELAXED,
                                           __HIP_MEMORY_SCOPE_AGENT);
          if ((it + 1) - (int)wv2 < LEAD) break;
          if (__hip_atomic_load(&g_T[0], __ATOMIC_RELAXED, __HIP_MEMORY_SCOPE_AGENT))
            break;
          if (g == 0) {                               // sweeper sweeps in-guard
            bool closed, allc; conv_scan(wv2, closed, allc);
            if (closed) {
              if (allc)
                __hip_atomic_store(&g_T[0], wv2 + 1u, __ATOMIC_RELAXED,
                                   __HIP_MEMORY_SCOPE_AGENT);
              __hip_atomic_store(&g_water[0], wv2 + 1u, __ATOMIC_RELAXED,
                                 __HIP_MEMORY_SCOPE_AGENT);
              continue;
            }
          }
          __builtin_amdgcn_s_sleep(4);
          if (++guard > (1ll << 22)) break;           // safety valve
        }
      }
    }
    // no trailing barrier: next iteration's B1 publishes the fresh s_ctl
  }

  // ---- tail: ran out of iterations without a resolved decision ----
  if (done_sT < 0) {
    if (t == 0) {
      if (g == 0) {  // sweeper finishes the sweep so others can exit
        unsigned w = __hip_atomic_load(&g_water[0], __ATOMIC_RELAXED,
                                       __HIP_MEMORY_SCOPE_AGENT);
        long long guard = 0;
        while (w < (unsigned)MAXIT &&
               __hip_atomic_load(&g_T[0], __ATOMIC_RELAXED,
                                 __HIP_MEMORY_SCOPE_AGENT) == 0u) {
          bool closed, allc; conv_scan(w, closed, allc);
          if (closed) {
            if (allc)
              __hip_atomic_store(&g_T[0], w + 1u, __ATOMIC_RELAXED,
                                 __HIP_MEMORY_SCOPE_AGENT);
            ++w;
            __hip_atomic_store(&g_water[0], w, __ATOMIC_RELAXED,
                               __HIP_MEMORY_SCOPE_AGENT);
          } else {
            __builtin_amdgcn_s_sleep(4);
            if (++guard > (1ll << 22)) break;          // safety valve
          }
        }
        __hip_atomic_store(&g_water[0], (unsigned)MAXIT, __ATOMIC_RELAXED,
                           __HIP_MEMORY_SCOPE_AGENT);
      }
      unsigned Tl = 0; long long guard = 0;
      for (;;) {
        Tl = __hip_atomic_load(&g_T[0], __ATOMIC_RELAXED, __HIP_MEMORY_SCOPE_AGENT);
        if (Tl) break;
        if (__hip_atomic_load(&g_water[0], __ATOMIC_RELAXED,
                              __HIP_MEMORY_SCOPE_AGENT) >= (unsigned)MAXIT) {
          Tl = __hip_atomic_load(&g_T[0], __ATOMIC_RELAXED, __HIP_MEMORY_SCOPE_AGENT);
          break;
        }
        __builtin_amdgcn_s_sleep(4);
        if (++guard > (1ll << 24)) break;              // safety valve
      }
      s_ctl = Tl;
    }
    __syncthreads();
    done_sT = s_ctl ? (int)s_ctl - 1 : (MAXIT - 1);
  }

  // ---- outputs, all from own ring slot sT (same block, same XCD — no fence) ----
  const int sT = done_sT;
  const int slot = sT & (RING - 1);
  out[(size_t)g * NPTS + t] =
      (float)g_rcls[slot][(size_t)g * NPTS + t];       // classification
  if (t < NCTR) {
    float4 cc = g_rcent[slot][(size_t)g * NCTR + t];   // centroids at T
    float *o = out + OUT_CENT + ((size_t)g * NCTR + t) * 3;
    o[0] = cc.x; o[1] = cc.y; o[2] = cc.z;
  }
  if (t < 256) {                                       // score: EXACT old f64 tree
    double s = 0.0;
    for (int k = 0; k < 4; ++k) {
      int nn = k * 256 + t;
      int c = g_rcls[slot][(size_t)g * NPTS + nn];
      float4 c4 = g_rcent[slot][(size_t)g * NCTR + c];
      s += (double)fabsf(__fsub_rn(spx[nn], c4.x)) +
           (double)fabsf(__fsub_rn(spy[nn], c4.y)) +
           (double)fabsf(__fsub_rn(spz[nn], c4.z));
    }
    for (int off = 32; off; off >>= 1) s += __shfl_down(s, off, 64);
    if (lane == 0) redd[wv] = s;
  }
  __syncthreads();
  if (t == 0) out[OUT_SCORE + g] = (float)(redd[0] + redd[1] + redd[2] + redd[3]);
}

extern "C" void kernel_launch(void *const *d_in, const int *in_sizes, int n_in,
                              void *d_out, int out_size, void *d_ws, size_t ws_size,
                              hipStream_t stream) {
  const float *pos = (const float *)d_in[0];
  float *out = (float *)d_out;
  (void)d_ws; (void)ws_size; (void)in_sizes; (void)n_in; (void)out_size;

  fps_kernel<<<NGRP, NTHRF, 0, stream>>>(pos);
  kmeans_kernel<<<NGRP, NTHR, 0, stream>>>(pos, out);
}

// Round 15
// 550.262 us; speedup vs baseline: 1.2155x; 1.2155x over previous
//
#include <hip/hip_runtime.h>
#include <math.h>

// SymmetricKMeans MI355X — R27: revert to R25 (553.2us best, absmax 0).
// R26 post-mortem: 4-wave FPS regressed 283->365us — the per-pick syncthreads
// + LDS winner exchange (~+300cy/pick) ate the 108cy distance-issue saving.
// Every multi-participant pick structure tried (4-wave barrier, bpermute,
// switch+ballot) lands at ~700+cy/pick; single-wave DPP = ~555cy/pick floor:
// {uniform LDS bcast ~100cy + 72 packed-dist instrs (144cy, 1 SIMD) + exact
// (max,min-idx) reduce ~200cy + index resolve ~100cy} x 512 dependent picks.
// kmeans (267us) is issue-bound: busy-CU VALUBusy ~74% in phase A.
// This file is byte-identical to R25.

#define NGRP   80
#define NPTS   1024
#define NCTR   512
#define MAXIT  300
#define NTHR   1024
#define RING   64
#define LEAD   48
#define OUT_CENT  81920
#define OUT_SCORE 204800

typedef float v2f __attribute__((ext_vector_type(2)));
static __device__ __forceinline__ v2f mk2(float a, float b) {
  v2f r; r.x = a; r.y = b; return r;
}

__device__ float4   g_cent[NGRP * NCTR];            // FPS output -> kmeans init
__device__ int      g_rcls[RING][NGRP * NPTS];      // per-iteration cls ring
__device__ float4   g_rcent[RING][NGRP * NCTR];     // per-iteration centroid ring
__device__ unsigned g_conv32[MAXIT][32];            // bytes[0..79]: 0=open/1=nc/2=conv
__device__ unsigned g_T[32];                        // 0 unset, else T (iters run)
__device__ unsigned g_water[32];                    // contiguous closed prefix

// ---------------- threefry2x32, exactly as JAX (partitionable path) ----------------
__device__ __forceinline__ void tf2x32(unsigned k0, unsigned k1,
                                       unsigned x0, unsigned x1,
                                       unsigned &o0, unsigned &o1) {
  unsigned ks2 = k0 ^ k1 ^ 0x1BD11BDAu;
#define RND(r) { x0 += x1; x1 = (x1 << (r)) | (x1 >> (32 - (r))); x1 ^= x0; }
  x0 += k0; x1 += k1;
  RND(13) RND(15) RND(26) RND(6)
  x0 += k1;  x1 += ks2 + 1u;
  RND(17) RND(29) RND(16) RND(24)
  x0 += ks2; x1 += k0 + 2u;
  RND(13) RND(15) RND(26) RND(6)
  x0 += k0;  x1 += k1 + 3u;
  RND(17) RND(29) RND(16) RND(24)
  x0 += k1;  x1 += ks2 + 4u;
  RND(13) RND(15) RND(26) RND(6)
  x0 += ks2; x1 += k0 + 5u;
#undef RND
  o0 = x0; o1 = x1;
}

// Fused-DPP steps (compiler folds update_dpp into the single-use consumer and
// inserts the exact hazard nops). old=0: masked-row lanes compute op(x, 0) —
// corrupts only lanes the lane-63 chain never reads.
#define DPP_MAXB(CTRL, RM)                                                   \
  bv = fmaxf(bv, __int_as_float(__builtin_amdgcn_update_dpp(                 \
           0, __float_as_int(bv), (CTRL), (RM), 0xF, true)));
#define DPP_MINB(CTRL, RM)                                                   \
  { unsigned d_ = (unsigned)__builtin_amdgcn_update_dpp(                     \
        0, (int)cand, (CTRL), (RM), 0xF, true);                              \
    cand = cand < d_ ? cand : d_; }

// 64-lane inclusive int scan (LLVM AtomicOptimizer sequence; integer => exact)
__device__ __forceinline__ int wave_iscan(int x) {
  x += __builtin_amdgcn_update_dpp(0, x, 0x111, 0xF, 0xF, true); // row_shr:1
  x += __builtin_amdgcn_update_dpp(0, x, 0x112, 0xF, 0xF, true); // row_shr:2
  x += __builtin_amdgcn_update_dpp(0, x, 0x114, 0xF, 0xF, true); // row_shr:4
  x += __builtin_amdgcn_update_dpp(0, x, 0x118, 0xF, 0xF, true); // row_shr:8
  x += __builtin_amdgcn_update_dpp(0, x, 0x142, 0xA, 0xF, true); // row_bcast:15
  x += __builtin_amdgcn_update_dpp(0, x, 0x143, 0xC, 0xF, true); // row_bcast:31
  return x;
}

// sweep helper: closed (all 80 bytes nonzero) / allconv (all == 2); relaxed.
__device__ __forceinline__ void conv_scan(unsigned w, bool &closed, bool &allc) {
  unsigned hz = 0u; bool ac = true;
#pragma unroll
  for (int i = 0; i < 20; ++i) {
    unsigned d = __hip_atomic_load(&g_conv32[w][i], __ATOMIC_RELAXED,
                                   __HIP_MEMORY_SCOPE_AGENT);
    hz |= (d - 0x01010101u) & ~d & 0x80808080u;   // haszero(d)
    ac = ac && (d == 0x02020202u);
  }
  closed = (hz == 0u); allc = ac;
}

// ---------------- FPS: one WAVE per group, 16 points/lane, packed pairs ----------------
__global__ __launch_bounds__(64) void fps_kernel(const float *__restrict__ pos) {
  const int g = blockIdx.x, t = threadIdx.x;
  const int e = g & 7;
  __shared__ float4 sp4[NPTS];
  {  // distributed kmeans-sync-state re-init (graph-safe; kmeans launches after)
    const int gid = g * 64 + t, stride = NGRP * 64;
    for (int k = gid; k < MAXIT * 32; k += stride) g_conv32[0][k] = 0u;
    if (gid == 0) { g_T[0] = 0u; g_water[0] = 0u; }
  }
  unsigned s0, s1, o0, o1;            // partitionable split + random_bits
  tf2x32(0u, 1u, 0u, 1u, s0, s1);
  tf2x32(s0, s1, 0u, (unsigned)g, o0, o1);
  int last = (int)((o0 ^ o1) & 1023u);

  const float *p = pos + (size_t)e * NPTS * 3;
  v2f xp[8], yp[8], zp[8], mdp[8];
  unsigned nva[16];                   // loop-invariant candidate ids 64k + t
#pragma unroll
  for (int q = 0; q < 8; ++q) {       // pair q = points (2q)*64+t, (2q+1)*64+t
    int n0 = (2 * q) * 64 + t, n1 = (2 * q + 1) * 64 + t;
    xp[q] = mk2(p[n0 * 3 + 0], p[n1 * 3 + 0]);
    yp[q] = mk2(p[n0 * 3 + 1], p[n1 * 3 + 1]);
    zp[q] = mk2(p[n0 * 3 + 2], p[n1 * 3 + 2]);
    sp4[n0] = make_float4(xp[q].x, yp[q].x, zp[q].x, 0.f);
    sp4[n1] = make_float4(xp[q].y, yp[q].y, zp[q].y, 0.f);
    mdp[q] = mk2(__int_as_float(0x7f800000), __int_as_float(0x7f800000));
  }
#pragma unroll
  for (int k = 0; k < 16; ++k) nva[k] = (unsigned)(k * 64 + t);
  __syncthreads();  // single wave: cross-lane LDS visibility
  for (int j = 0; j < NCTR; ++j) {
    const float4 L = sp4[last];       // one b128 broadcast read
    if (t == 0) {   // centroid j = p[last]; c2 plain chain (unchanged)
      float c2 = __fadd_rn(__fadd_rn(__fmul_rn(L.x, L.x), __fmul_rn(L.y, L.y)),
                           __fmul_rn(L.z, L.z));
      g_cent[(size_t)g * NCTR + j] = make_float4(L.x, L.y, L.z, c2);
    }
    {
#pragma clang fp contract(off)
      // packed distances: identical per-element op sequence (sub,mul,add,add,min)
      const v2f lx2 = mk2(L.x, L.x), ly2 = mk2(L.y, L.y), lz2 = mk2(L.z, L.z);
#pragma unroll
      for (int q = 0; q < 8; ++q) {
        v2f dx = xp[q] - lx2, dy = yp[q] - ly2, dz = zp[q] - lz2;
        v2f d = (dx * dx + dy * dy) + dz * dz;
        mdp[q] = __builtin_elementwise_min(mdp[q], d);   // == fminf per elem
      }
    }
    // ---- value phase: gmax (exact max; any order) ----
    v2f m01 = __builtin_elementwise_max(mdp[0], mdp[1]);
    v2f m23 = __builtin_elementwise_max(mdp[2], mdp[3]);
    v2f m45 = __builtin_elementwise_max(mdp[4], mdp[5]);
    v2f m67 = __builtin_elementwise_max(mdp[6], mdp[7]);
    v2f m03 = __builtin_elementwise_max(m01, m23);
    v2f m47 = __builtin_elementwise_max(m45, m67);
    v2f m07 = __builtin_elementwise_max(m03, m47);
    float bv = fmaxf(m07.x, m07.y);
    DPP_MAXB(0x121, 0xF)   // row_ror:1
    DPP_MAXB(0x122, 0xF)   // row_ror:2
    DPP_MAXB(0x124, 0xF)   // row_ror:4
    DPP_MAXB(0x128, 0xF)   // row_ror:8  -> every lane holds its row-of-16 max
    DPP_MAXB(0x142, 0xA)   // row_bcast:15 (rows 1,3)
    DPP_MAXB(0x143, 0xC)   // row_bcast:31 (rows 2,3) -> lane 63 = global max
    const float gmax = __int_as_float(
        __builtin_amdgcn_readlane(__float_as_int(bv), 63));  // uniform SGPR

    // ---- index phase: last = min{ n : md[n]==gmax } (== first-max) ----
    // 16 INDEPENDENT selects (chain depth 1) + pairwise min tree (depth 4,
    // clang fuses pairs to v_min3_u32).
    unsigned cd[16];
#pragma unroll
    for (int k = 0; k < 16; ++k) {
      const float mv = (k & 1) ? mdp[k >> 1].y : mdp[k >> 1].x;
      cd[k] = (mv == gmax) ? nva[k] : 0x7fffffffu;
    }
#pragma unroll
    for (int s = 8; s >= 1; s >>= 1)
#pragma unroll
      for (int i = 0; i < s; ++i) cd[i] = cd[i] < cd[i + s] ? cd[i] : cd[i + s];
    unsigned cand = cd[0];
    DPP_MINB(0x121, 0xF)
    DPP_MINB(0x122, 0xF)
    DPP_MINB(0x124, 0xF)
    DPP_MINB(0x128, 0xF)
    DPP_MINB(0x142, 0xA)
    DPP_MINB(0x143, 0xC)              // lane 63 = min candidate id
    last = (int)__builtin_amdgcn_readlane((int)cand, 63);   // SGPR broadcast
  }
}

// ---------------- persistent decoupled k-means: 1 block = 1 group ----------------
__global__ __launch_bounds__(NTHR) void kmeans_kernel(
    const float *__restrict__ pos, float *__restrict__ out) {
  const int g = blockIdx.x, t = threadIdx.x;
  const int e = g & 7;
  const int lane = t & 63, wv = t >> 6;

  // centroid LDS in stripe-pair layout (R16): scp[q] = {x_a,x_b,y_a,y_b,z_a,z_b,w_a,w_b}
  __shared__ float  scp[NCTR / 2][8];
  __shared__ float  spx[NPTS], spy[NPTS], spz[NPTS];
  __shared__ int    slab[NPTS];
  __shared__ int    cnt[NCTR], offs[NCTR];
  __shared__ int    idx[NPTS];
  __shared__ float  redf[16];
  __shared__ double redd[4];
  __shared__ int    swtot[8];
  __shared__ unsigned s_ctl;

  const int cc7 = t & 127, cbid = (t >> 7) & 3;
  const int cq = cc7 + (cbid >> 1) * 128, cs = cbid & 1;  // centroid t's LDS slot

  {  // stage points + initial centroids (once)
    const float *gp = pos + (size_t)e * NPTS * 3;
    spx[t] = gp[t * 3 + 0]; spy[t] = gp[t * 3 + 1]; spz[t] = gp[t * 3 + 2];
    if (t < NCTR) {
      float4 cc = g_cent[(size_t)g * NCTR + t];
      scp[cq][0 + cs] = cc.x; scp[cq][2 + cs] = cc.y;
      scp[cq][4 + cs] = cc.z; scp[cq][6 + cs] = cc.w;
    }
    if (t == 0) s_ctl = 0u;
  }
  __syncthreads();

  const float px = spx[t], py = spy[t], pz = spz[t];
  const float p2 = __fadd_rn(__fadd_rn(__fmul_rn(px, px), __fmul_rn(py, py)),
                             __fmul_rn(pz, pz));
  const v2f px2 = mk2(px, px), py2 = mk2(py, py), pz2 = mk2(pz, pz);
  const v2f p22 = mk2(p2, p2), nw2 = mk2(-2.0f, -2.0f);

  int done_sT = -1;
  for (int it = 0; it < MAXIT; ++it) {
    // ---- phase A: stripe-4 argmin, packed pairs. fma(-2,t0,p2) is bit-equal
    // to (p2 - 2*t0): 2*t0 is exact (exponent bump), one rounding either way.
    float best0 = __int_as_float(0x7f800000), best1 = best0,
          best2 = best0, best3 = best0;
    int im0 = 0, im1 = 0, im2 = 0, im3 = 0;
    {
#pragma clang fp contract(off)
#pragma unroll 2
      for (int m = 0; m < NCTR / 4; ++m) {
        const float4 lo0 = *(const float4 *)&scp[m][0];       // x_a x_b y_a y_b
        const float4 hi0 = *(const float4 *)&scp[m][4];       // z_a z_b w_a w_b
        const float4 lo1 = *(const float4 *)&scp[m + 128][0];
        const float4 hi1 = *(const float4 *)&scp[m + 128][4];
        v2f t0 = px2 * mk2(lo0.x, lo0.y);                     // mul
        t0 = __builtin_elementwise_fma(py2, mk2(lo0.z, lo0.w), t0);  // fma
        t0 = __builtin_elementwise_fma(pz2, mk2(hi0.x, hi0.y), t0);  // fma
        v2f dA = __builtin_elementwise_fma(nw2, t0, p22) + mk2(hi0.z, hi0.w);
        v2f t1 = px2 * mk2(lo1.x, lo1.y);
        t1 = __builtin_elementwise_fma(py2, mk2(lo1.z, lo1.w), t1);
        t1 = __builtin_elementwise_fma(pz2, mk2(hi1.x, hi1.y), t1);
        v2f dB = __builtin_elementwise_fma(nw2, t1, p22) + mk2(hi1.z, hi1.w);
        float d0 = dA.x, d1 = dA.y, d2 = dB.x, d3 = dB.y;
        if (d0 < best0) { best0 = d0; im0 = m; }
        if (d1 < best1) { best1 = d1; im1 = m; }
        if (d2 < best2) { best2 = d2; im2 = m; }
        if (d3 < best3) { best3 = d3; im3 = m; }
      }
    }
    float best = best0; int bm = im0;                 // stripe priority = m order
    if (best1 < best) { best = best1; bm = 128 + im1; }
    if (best2 < best) { best = best2; bm = 256 + im2; }
    if (best3 < best) { best = best3; bm = 384 + im3; }
    const int slot = it & (RING - 1);
    g_rcls[slot][(size_t)g * NPTS + t] = bm;          // self-read ring (no fence)
    slab[t] = bm;
    if (t < NCTR) cnt[t] = 0;                         // merged into B1 region
    if (t == 0)                                       // fresh T read (R23)
      s_ctl = __hip_atomic_load(&g_T[0], __ATOMIC_RELAXED,
                                __HIP_MEMORY_SCOPE_AGENT);
    __syncthreads();                                  // B1 (publishes s_ctl)

    // ---- exit check: s_ctl = freshest known T ----
    {
      const unsigned tv = s_ctl;
      if (it > 0 && tv != 0u && (int)tv <= it) {      // ring slot T-1 complete
        done_sT = (int)tv - 1;
        break;
      }
    }

    // ---- phase B (single block; same f32 op order as R16-R25) ----
    atomicAdd(&cnt[slab[t]], 1);                      // 1024 integer adds
    __syncthreads();
    int sc = 0;
    if (t < NCTR) {                                   // DPP scan (waves 0..7)
      sc = wave_iscan(cnt[t]);
      if (lane == 63) swtot[wv] = sc;
    }
    __syncthreads();
    if (t < NCTR) {
      int pre = 0;
#pragma unroll
      for (int w = 0; w < 8; ++w) pre += (w < wv) ? swtot[w] : 0;
      offs[t] = sc + pre;                             // incl[t]
      cnt[t] = 0;                                     // reuse as wctr
    }
    __syncthreads();
    {
      int c0 = slab[t]; int sl0 = atomicAdd(&cnt[c0], 1);
      idx[(c0 ? offs[c0 - 1] : 0) + sl0] = t;         // scatter (sorted below)
    }
    __syncthreads();
    float mx = 0.0f;
    if (t < NCTR) {
      const int c = t;                                // one centroid per thread
      const int base = c ? offs[c - 1] : 0;
      const int kk = offs[c] - base;
      for (int i = base + 1; i < base + kk; ++i) {    // ascending point order
        int v = idx[i], j = i - 1;
        while (j >= base && idx[j] > v) { idx[j + 1] = idx[j]; --j; }
        idx[j + 1] = v;
      }
      float4 oldc;                                    // gather from pair layout
      oldc.x = scp[cq][0 + cs]; oldc.y = scp[cq][2 + cs];
      oldc.z = scp[cq][4 + cs]; oldc.w = scp[cq][6 + cs];
      float nx, ny, nz;
      if (kk > 0) {
        float sxx = 0.f, syy = 0.f, szz = 0.f;
        for (int i = 0; i < kk; ++i) {                // same adds, same order
          int n2 = idx[base + i];
          sxx = __fadd_rn(sxx, spx[n2]);
          syy = __fadd_rn(syy, spy[n2]);
          szz = __fadd_rn(szz, spz[n2]);
        }
        float fc = (float)kk;
        nx = __fdiv_rn(sxx, fc); ny = __fdiv_rn(syy, fc); nz = __fdiv_rn(szz, fc);
      } else { nx = oldc.x; ny = oldc.y; nz = oldc.z; }
      float dx = __fsub_rn(oldc.x, nx), dy = __fsub_rn(oldc.y, ny),
            dz = __fsub_rn(oldc.z, nz);
      float nr = __fsqrt_rn(__fadd_rn(__fadd_rn(__fmul_rn(dx, dx), __fmul_rn(dy, dy)),
                                      __fmul_rn(dz, dz)));
      mx = nr;
      float c2v2 = __fadd_rn(__fadd_rn(__fmul_rn(nx, nx), __fmul_rn(ny, ny)),
                             __fmul_rn(nz, nz));
      scp[cq][0 + cs] = nx; scp[cq][2 + cs] = ny;     // LDS-persistent update
      scp[cq][4 + cs] = nz; scp[cq][6 + cs] = c2v2;
      g_rcent[slot][(size_t)g * NCTR + t] =           // self-read ring snapshot
          make_float4(nx, ny, nz, c2v2);
    }
    for (int off = 32; off; off >>= 1) {              // wave max (waves 8-15: 0)
      float o = __shfl_down(mx, off, 64);
      if (o > mx) mx = o;
    }
    if (lane == 0) redf[wv] = mx;
    __syncthreads();                                  // E1: redf + scp complete

    // ---- control (t0 only, ALL RELAXED — no cache-maintenance ops) ----
    if (t == 0) {
      unsigned Tl = __hip_atomic_load(&g_T[0], __ATOMIC_RELAXED, __HIP_MEMORY_SCOPE_AGENT);
      if (Tl == 0u) {
        float bmx = fmaxf(fmaxf(fmaxf(redf[0], redf[1]), fmaxf(redf[2], redf[3])),
                          fmaxf(fmaxf(redf[4], redf[5]), fmaxf(redf[6], redf[7])));
        unsigned char cv = (bmx < 1e-3f) ? (unsigned char)2 : (unsigned char)1;
        __hip_atomic_store((unsigned char *)&g_conv32[it][0] + g, cv,
                           __ATOMIC_RELAXED, __HIP_MEMORY_SCOPE_AGENT);
        if (g == 0) {                                 // sweeper
          unsigned w = __hip_atomic_load(&g_water[0], __ATOMIC_RELAXED,
                                         __HIP_MEMORY_SCOPE_AGENT);
          const unsigned w0 = w;
          while (w <= (unsigned)it) {
            bool closed, allc; conv_scan(w, closed, allc);
            if (!closed) break;
            if (allc) {                               // first all-conv t => T
              Tl = w + 1u;
              __hip_atomic_store(&g_T[0], Tl, __ATOMIC_RELAXED, __HIP_MEMORY_SCOPE_AGENT);
              ++w; break;
            }
            ++w;
          }
          if (w != w0)
            __hip_atomic_store(&g_water[0], w, __ATOMIC_RELAXED, __HIP_MEMORY_SCOPE_AGENT);
        }
        if (Tl == 0u)
          Tl = __hip_atomic_load(&g_T[0], __ATOMIC_RELAXED, __HIP_MEMORY_SCOPE_AGENT);
      }
      if (Tl == 0u && it + 1 >= LEAD) {               // ring overwrite guard
        long long guard = 0;
        for (;;) {
          unsigned wv2 = __hip_atomic_load(&g_water[0], __ATOMIC_RELAXED,
                                           __HIP_MEMORY_SCOPE_AGENT);
          if ((it + 1) - (int)wv2 < LEAD) break;
          if (__hip_atomic_load(&g_T[0], __ATOMIC_RELAXED, __HIP_MEMORY_SCOPE_AGENT))
            break;
          if (g == 0) {                               // sweeper sweeps in-guard
            bool closed, allc; conv_scan(wv2, closed, allc);
            if (closed) {
              if (allc)
                __hip_atomic_store(&g_T[0], wv2 + 1u, __ATOMIC_RELAXED,
                                   __HIP_MEMORY_SCOPE_AGENT);
              __hip_atomic_store(&g_water[0], wv2 + 1u, __ATOMIC_RELAXED,
                                 __HIP_MEMORY_SCOPE_AGENT);
              continue;
            }
          }
          __builtin_amdgcn_s_sleep(4);
          if (++guard > (1ll << 22)) break;           // safety valve
        }
      }
    }
    // no trailing barrier: next iteration's B1 publishes the fresh s_ctl
  }

  // ---- tail: ran out of iterations without a resolved decision ----
  if (done_sT < 0) {
    if (t == 0) {
      if (g == 0) {  // sweeper finishes the sweep so others can exit
        unsigned w = __hip_atomic_load(&g_water[0], __ATOMIC_RELAXED,
                                       __HIP_MEMORY_SCOPE_AGENT);
        long long guard = 0;
        while (w < (unsigned)MAXIT &&
               __hip_atomic_load(&g_T[0], __ATOMIC_RELAXED,
                                 __HIP_MEMORY_SCOPE_AGENT) == 0u) {
          bool closed, allc; conv_scan(w, closed, allc);
          if (closed) {
            if (allc)
              __hip_atomic_store(&g_T[0], w + 1u, __ATOMIC_RELAXED,
                                 __HIP_MEMORY_SCOPE_AGENT);
            ++w;
            __hip_atomic_store(&g_water[0], w, __ATOMIC_RELAXED,
                               __HIP_MEMORY_SCOPE_AGENT);
          } else {
            __builtin_amdgcn_s_sleep(4);
            if (++guard > (1ll << 22)) break;          // safety valve
          }
        }
        __hip_atomic_store(&g_water[0], (unsigned)MAXIT, __ATOMIC_RELAXED,
                           __HIP_MEMORY_SCOPE_AGENT);
      }
      unsigned Tl = 0; long long guard = 0;
      for (;;) {
        Tl = __hip_atomic_load(&g_T[0], __ATOMIC_RELAXED, __HIP_MEMORY_SCOPE_AGENT);
        if (Tl) break;
        if (__hip_atomic_load(&g_water[0], __ATOMIC_RELAXED,
                              __HIP_MEMORY_SCOPE_AGENT) >= (unsigned)MAXIT) {
          Tl = __hip_atomic_load(&g_T[0], __ATOMIC_RELAXED, __HIP_MEMORY_SCOPE_AGENT);
          break;
        }
        __builtin_amdgcn_s_sleep(4);
        if (++guard > (1ll << 24)) break;              // safety valve
      }
      s_ctl = Tl;
    }
    __syncthreads();
    done_sT = s_ctl ? (int)s_ctl - 1 : (MAXIT - 1);
  }

  // ---- outputs, all from own ring slot sT (same block, same XCD — no fence) ----
  const int sT = done_sT;
  const int slot = sT & (RING - 1);
  out[(size_t)g * NPTS + t] =
      (float)g_rcls[slot][(size_t)g * NPTS + t];       // classification
  if (t < NCTR) {
    float4 cc = g_rcent[slot][(size_t)g * NCTR + t];   // centroids at T
    float *o = out + OUT_CENT + ((size_t)g * NCTR + t) * 3;
    o[0] = cc.x; o[1] = cc.y; o[2] = cc.z;
  }
  if (t < 256) {                                       // score: EXACT old f64 tree
    double s = 0.0;
    for (int k = 0; k < 4; ++k) {
      int nn = k * 256 + t;
      int c = g_rcls[slot][(size_t)g * NPTS + nn];
      float4 c4 = g_rcent[slot][(size_t)g * NCTR + c];
      s += (double)fabsf(__fsub_rn(spx[nn], c4.x)) +
           (double)fabsf(__fsub_rn(spy[nn], c4.y)) +
           (double)fabsf(__fsub_rn(spz[nn], c4.z));
    }
    for (int off = 32; off; off >>= 1) s += __shfl_down(s, off, 64);
    if (lane == 0) redd[wv] = s;
  }
  __syncthreads();
  if (t == 0) out[OUT_SCORE + g] = (float)(redd[0] + redd[1] + redd[2] + redd[3]);
}

extern "C" void kernel_launch(void *const *d_in, const int *in_sizes, int n_in,
                              void *d_out, int out_size, void *d_ws, size_t ws_size,
                              hipStream_t stream) {
  const float *pos = (const float *)d_in[0];
  float *out = (float *)d_out;
  (void)d_ws; (void)ws_size; (void)in_sizes; (void)n_in; (void)out_size;

  fps_kernel<<<NGRP, 64, 0, stream>>>(pos);
  kmeans_kernel<<<NGRP, NTHR, 0, stream>>>(pos, out);
}